// Round 4
// baseline (94.090 us; speedup 1.0000x reference)
//
#include <hip/hip_runtime.h>

// ---------------------------------------------------------------------------
// DWT autoencoder round trip. Level-2 dwt2+idwt2 cancel exactly -> LL1r==LL1.
//   K0: rearrange conv weights into exact consumption order
//   K1: register-only fused haar-dwt + conv3x3 s2 (no LDS, no barrier):
//       each thread owns one y pixel; per (ch,a) it loads its 2x6 x-strip,
//       computes the band row in registers, FMAs into 9 accumulators.
//       Writes LL1 (B,3,256,256) + y (B,9,128,128).
//   K2: convT4x4 s2 of y -> l1 bands, fused with idwt2(LL1, l1) -> out
// B=32, C=3, H=W=512.
// R3 lesson: K1's 39KB LDS capped occupancy at 4 blocks/CU (39%) and the
// stage->barrier->conv chain left both pipes idle. Register-DWT removes LDS.
// ---------------------------------------------------------------------------

#define BB 32

// K0: wd2[((ch*3+a)*3+q)*27 + band*9 + o] = 0.5 * dw[o, ch*3+band, a, q]
//     (0.5 = the DWT band scale, folded into the conv weight)
//     wu [((cin*4+rt*2+ct)*4+di*2+dj)*9+o] = uw[cin, o, 3-di-2rt, 3-dj-2ct]
__global__ __launch_bounds__(256) void k0_rearrange(
    const float* __restrict__ dw, const float* __restrict__ uw,
    float* __restrict__ wd, float* __restrict__ wu)
{
    const int t = threadIdx.x;
    for (int i = t; i < 729; i += 256) {
        const int o    = i % 9;
        const int band = (i / 9) % 3;
        const int q    = (i / 27) % 3;
        const int a    = (i / 81) % 3;
        const int ch   = i / 243;
        wd[i] = 0.5f * dw[o * 81 + (ch * 3 + band) * 9 + a * 3 + q];
    }
    for (int i = t; i < 1296; i += 256) {
        const int o = i % 9; int r = i / 9;
        const int dj = r & 1; const int di = (r >> 1) & 1; r >>= 2;
        const int ct = r & 1; const int rt = (r >> 1) & 1; const int cin = r >> 2;
        wu[i] = uw[cin * 144 + o * 16 + (3 - di - 2 * rt) * 4 + (3 - dj - 2 * ct)];
    }
}

// K1: one thread per y pixel (I,J). Band window rows r=2I-1+a use x rows
// {2r,2r+1} = disjoint across a; cols 4J-2..4J+3 (1.5x overlap via L1).
__global__ __launch_bounds__(256) void k1_dwt_down(
    const float* __restrict__ x,     // (B,3,512,512)
    const float* __restrict__ wd,    // reordered (ch,a,q,band,o), x0.5 folded
    const float* __restrict__ db,    // (9)
    float* __restrict__ LL1,         // (B,3,256,256)
    float* __restrict__ y)           // (B,9,128,128)
{
    const int t    = threadIdx.x;
    const int b    = blockIdx.x >> 6;
    const int tile = blockIdx.x & 63;
    const int I    = ((tile >> 3) << 4) + (t >> 4);   // 0..127
    const int J    = ((tile & 7) << 4) + (t & 15);    // 0..127

    float acc[9];
#pragma unroll
    for (int o = 0; o < 9; ++o) acc[o] = db[o];

    const bool jok  = (J > 0);
    const int  cofs = jok ? -2 : 0;   // clamped address for the left halo pair

#pragma unroll
    for (int ch = 0; ch < 3; ++ch) {
        const float* xc  = x + ((size_t)b * 3 + ch) * 512 * 512;
        float*       llc = LL1 + ((size_t)b * 3 + ch) * 256 * 256;
#pragma unroll
        for (int a = 0; a < 3; ++a) {
            const int  r   = 2 * I - 1 + a;          // level-1 row
            const bool rok = (r >= 0);               // false only if a==0&&I==0
            const int  xr  = rok ? 2 * r : 0;        // clamped x row
            const float* row0 = xc + (size_t)xr * 512 + 4 * J;
            const float* row1 = row0 + 512;

            float2 a0 = *reinterpret_cast<const float2*>(row0 + cofs);
            float2 a1 = *reinterpret_cast<const float2*>(row0);
            float2 a2 = *reinterpret_cast<const float2*>(row0 + 2);
            float2 b0 = *reinterpret_cast<const float2*>(row1 + cofs);
            float2 b1 = *reinterpret_cast<const float2*>(row1);
            float2 b2 = *reinterpret_cast<const float2*>(row1 + 2);
            if (!jok) { a0.x = a0.y = b0.x = b0.y = 0.f; }
            if (!rok) {
                a0.x = a0.y = a1.x = a1.y = a2.x = a2.y = 0.f;
                b0.x = b0.y = b1.x = b1.y = b2.x = b2.y = 0.f;
            }

            // band row (unscaled by 0.5; scale folded into wd)
            float lh[3], hl[3], hh[3], llq1, llq2;
            {
                const float s0 = a0.x + a0.y, d0 = a0.x - a0.y;
                const float s1 = b0.x + b0.y, d1 = b0.x - b0.y;
                lh[0] = s0 - s1; hl[0] = d0 + d1; hh[0] = d0 - d1;
            }
            {
                const float s0 = a1.x + a1.y, d0 = a1.x - a1.y;
                const float s1 = b1.x + b1.y, d1 = b1.x - b1.y;
                lh[1] = s0 - s1; hl[1] = d0 + d1; hh[1] = d0 - d1;
                llq1 = (s0 + s1) * 0.5f;
            }
            {
                const float s0 = a2.x + a2.y, d0 = a2.x - a2.y;
                const float s1 = b2.x + b2.y, d1 = b2.x - b2.y;
                lh[2] = s0 - s1; hl[2] = d0 + d1; hh[2] = d0 - d1;
                llq2 = (s0 + s1) * 0.5f;
            }

            // LL1 write: thread owns level-1 rows {2I,2I+1} (a=1,2), cols {2J,2J+1}
            if (a >= 1) {
                float2 llv; llv.x = llq1; llv.y = llq2;
                *reinterpret_cast<float2*>(llc + (size_t)r * 256 + 2 * J) = llv;
            }

            // conv FMAs: 3 cols x 3 bands x 9 outs, consecutive uniform weights
            const float* wg = wd + ((ch * 3 + a) * 3) * 27;
#pragma unroll
            for (int q = 0; q < 3; ++q) {
                const float* w0 = wg + q * 27;
#pragma unroll
                for (int o = 0; o < 9; ++o) acc[o] += lh[q] * w0[o];
#pragma unroll
                for (int o = 0; o < 9; ++o) acc[o] += hl[q] * w0[9 + o];
#pragma unroll
                for (int o = 0; o < 9; ++o) acc[o] += hh[q] * w0[18 + o];
            }
        }
    }

#pragma unroll
    for (int o = 0; o < 9; ++o)
        y[(((size_t)b * 9 + o) * 128 + I) * 128 + J] = acc[o];
}

// K2: one block = one batch image, a 32x32 tile at 256-res (=> 64x64 output
// pixels at 512-res), all 3 colors. Each thread owns a 2x2 parity quad; all
// 36 accumulators live (needs VGPR room -> launch_bounds(256,4)).
__global__ __launch_bounds__(256, 4) void k2_up_idwt(
    const float* __restrict__ yg,    // (B,9,128,128)
    const float* __restrict__ wu,    // reordered (cin,rt,ct,di,dj,o)
    const float* __restrict__ ub,    // (9)
    const float* __restrict__ LL1,   // (B,3,256,256)
    float* __restrict__ out)         // (B,3,512,512)
{
    __shared__ float ysh[9][18][19];

    const int t    = threadIdx.x;
    const int b    = blockIdx.x >> 6;
    const int tile = blockIdx.x & 63;
    const int r0   = (tile >> 3) << 5;  // 256-res tile origin
    const int c0   = (tile & 7) << 5;
    const int p0   = (r0 >> 1) - 1;     // y row of local 0
    const int q0   = (c0 >> 1) - 1;

    // ---- stage y tile (18x18 halo, 9 ch) into LDS ----
    for (int item = t; item < 9 * 324; item += 256) {
        const int cin = item / 324;
        int rem       = item - cin * 324;
        const int lp  = rem / 18;
        const int lq  = rem - lp * 18;
        const int p   = p0 + lp, q = q0 + lq;
        float v = 0.f;
        if (p >= 0 && p < 128 && q >= 0 && q < 128)
            v = yg[(((size_t)b * 9 + cin) * 128 + p) * 128 + q];
        ysh[cin][lp][lq] = v;
    }
    __syncthreads();

    const int i2 = t >> 4;   // 0..15
    const int j2 = t & 15;   // 0..15

    float acc[2][2][9];      // [di][dj][out-ch]
#pragma unroll
    for (int di = 0; di < 2; ++di)
#pragma unroll
        for (int dj = 0; dj < 2; ++dj)
#pragma unroll
            for (int o = 0; o < 9; ++o) acc[di][dj][o] = ub[o];

    for (int cin = 0; cin < 9; ++cin) {
        float yv[3][3];
#pragma unroll
        for (int r = 0; r < 3; ++r)
#pragma unroll
            for (int c = 0; c < 3; ++c)
                yv[r][c] = ysh[cin][i2 + r][j2 + c];
        const float* wc = wu + cin * 144;
#pragma unroll
        for (int rt = 0; rt < 2; ++rt)
#pragma unroll
            for (int ct = 0; ct < 2; ++ct) {
                const float* wg = wc + (rt * 2 + ct) * 36;  // 36 consecutive
#pragma unroll
                for (int di = 0; di < 2; ++di)
#pragma unroll
                    for (int dj = 0; dj < 2; ++dj) {
                        const float vv = yv[di + rt][dj + ct];
                        const float* w9 = wg + (di * 2 + dj) * 9;
#pragma unroll
                        for (int o = 0; o < 9; ++o)
                            acc[di][dj][o] += vv * w9[o];
                    }
            }
    }

    // ---- epilogue: idwt2(LL1, LH, HL, HH) -> 4x4 output pixels / color ----
#pragma unroll
    for (int cc = 0; cc < 3; ++cc) {
#pragma unroll
        for (int di = 0; di < 2; ++di) {
            const int I = r0 + 2 * i2 + di;
            const int J = c0 + 2 * j2;
            const float2 llv = *reinterpret_cast<const float2*>(
                LL1 + (((size_t)b * 3 + cc) * 256 + I) * 256 + J);
            float4 top, bot;
            {
                const float ll = llv.x;
                const float lh = acc[di][0][cc * 3 + 0];
                const float hl = acc[di][0][cc * 3 + 1];
                const float hh = acc[di][0][cc * 3 + 2];
                const float e0 = ll + lh, od0 = ll - lh;
                const float e1 = hl + hh, od1 = hl - hh;
                top.x = (e0 + e1) * 0.5f; top.y = (e0 - e1) * 0.5f;
                bot.x = (od0 + od1) * 0.5f; bot.y = (od0 - od1) * 0.5f;
            }
            {
                const float ll = llv.y;
                const float lh = acc[di][1][cc * 3 + 0];
                const float hl = acc[di][1][cc * 3 + 1];
                const float hh = acc[di][1][cc * 3 + 2];
                const float e0 = ll + lh, od0 = ll - lh;
                const float e1 = hl + hh, od1 = hl - hh;
                top.z = (e0 + e1) * 0.5f; top.w = (e0 - e1) * 0.5f;
                bot.z = (od0 + od1) * 0.5f; bot.w = (od0 - od1) * 0.5f;
            }
            float* op = out + (((size_t)b * 3 + cc) * 512 + 2 * I) * 512 + 2 * J;
            *reinterpret_cast<float4*>(op) = top;
            *reinterpret_cast<float4*>(op + 512) = bot;
        }
    }
}

extern "C" void kernel_launch(void* const* d_in, const int* in_sizes, int n_in,
                              void* d_out, int out_size, void* d_ws, size_t ws_size,
                              hipStream_t stream) {
    const float* x  = (const float*)d_in[0];
    const float* dw = (const float*)d_in[1];
    const float* db = (const float*)d_in[2];
    const float* uw = (const float*)d_in[3];
    const float* ub = (const float*)d_in[4];
    float* outp = (float*)d_out;

    float* wsf = (float*)d_ws;
    float* wd  = wsf;            // 729 floats (pad to 768)
    float* wu  = wsf + 768;      // 1296 floats (pad to 1536)
    float* LL1 = wsf + 2304;                         // 25.2 MB
    float* y   = LL1 + (size_t)BB * 3 * 256 * 256;   // 18.9 MB

    k0_rearrange<<<dim3(1), dim3(256), 0, stream>>>(dw, uw, wd, wu);
    k1_dwt_down<<<dim3(BB * 64), dim3(256), 0, stream>>>(x, wd, db, LL1, y);
    k2_up_idwt<<<dim3(BB * 64), dim3(256), 0, stream>>>(y, wu, ub, LL1, outp);
}